// Round 4
// baseline (99.963 us; speedup 1.0000x reference)
//
#include <hip/hip_runtime.h>
#include <hip/hip_bf16.h>

#define N_ATOMS 1024
#define HIDDEN  64
#define TM      32      // atoms per K2 block
#define FSTRIDE 36      // ws floats per atom (34 used, padded for alignment)
#define QCAP    67      // wave-private queue entries (64 max + 3 zero-pad)

// ---------------- K1: pairwise env features ----------------
// One wave per atom, 4 atoms (same batch) per 256-thread block.
// Stage all 1024 neighbors (x,y,z,typesign) into LDS SoA once (coalesced,
// one barrier). 16 sweeps of 64 neighbors: distance + cutoff; survivors
// compacted into a wave-private LDS queue (prefix popcount, no atomics);
// queue drained 4 entries/iter with lanes = (slot 0..3) x (rbf 0..15),
// each lane feeding both species accumulators. 2 shfl_xor reduce.
// Writes 34 features per atom to ws (stride FSTRIDE).
__global__ __launch_bounds__(256) void k1_env(
    const float* __restrict__ pos,    // [B,1024,3]
    const int*   __restrict__ types,  // [B,1024]
    float*       __restrict__ ws)     // [B*1024, FSTRIDE]
{
    const int tid  = threadIdx.x;
    const int lane = tid & 63;
    const int wav  = tid >> 6;
    const int a    = blockIdx.x * 4 + wav;   // global atom
    const int bidx = a >> 10;
    const int i    = a & (N_ATOMS - 1);

    // SoA neighbor data: x[0..1023], y[1024..], z[2048..], tsign[3072..]
    __shared__ float sdat[4 * N_ATOMS];
    __shared__ float qbuf[4 * QCAP * 2];     // per-wave (d, m) queue

    // ---- stage neighbors (coalesced float4/int4), one barrier ----
    {
        const float* pf = pos + (size_t)bidx * (N_ATOMS * 3);
#pragma unroll
        for (int rep = 0; rep < 3; ++rep) {
            const int f0 = rep * 1024 + tid * 4;
            const float4 v = *(const float4*)(pf + f0);
#pragma unroll
            for (int q = 0; q < 4; ++q) {
                const int f  = f0 + q;
                const int j  = f / 3;
                const int cc = f - j * 3;
                sdat[cc * N_ATOMS + j] = (&v.x)[q];
            }
        }
        const int4 tv = *(const int4*)(types + (size_t)bidx * N_ATOMS + tid * 4);
        float4 tsv;
        tsv.x = (tv.x == 0) ? 1.0f : -1.0f;
        tsv.y = (tv.y == 0) ? 1.0f : -1.0f;
        tsv.z = (tv.z == 0) ? 1.0f : -1.0f;
        tsv.w = (tv.w == 0) ? 1.0f : -1.0f;
        *(float4*)&sdat[3 * N_ATOMS + tid * 4] = tsv;
    }
    __syncthreads();

    const float xi = sdat[i];
    const float yi = sdat[N_ATOMS + i];
    const float zi = sdat[2 * N_ATOMS + i];

    const int   slot = lane >> 4;                    // 0..3
    const int   r16  = lane & 15;                    // rbf this lane owns
    const float c    = (float)r16 * (2.5f / 15.0f);  // rbf center
    const int   qb   = wav * (QCAP * 2);             // queue base (floats)

    float acc0 = 0.0f;   // env[r][species 0] partial (slot-split)
    float acc1 = 0.0f;   // env[r][species 1] partial

    for (int s = 0; s < N_ATOMS / 64; ++s) {
        const int jj = lane + s * 64;
        const float px  = sdat[jj];
        const float py  = sdat[N_ATOMS + jj];
        const float pz  = sdat[2 * N_ATOMS + jj];
        const float tsj = sdat[3 * N_ATOMS + jj];
        const float dx = xi - px, dy = yi - py, dz = zi - pz;
        const float sq = dx * dx + dy * dy + dz * dz;
        const bool pred = (jj != i) && (sq < 6.25f);

        const unsigned long long mask = __ballot(pred);
        const int ns = (int)__popcll(mask);

        if (pred) {
            const float d  = sqrtf(sq);
            const float x  = d * 0.4f;
            const float x3 = x * x * x;
            const float cutv = 1.0f + x3 * (-10.0f + x * (15.0f - 6.0f * x));
            const int idx = (int)__popcll(mask & ((1ull << lane) - 1ull));
            *(float2*)&qbuf[qb + idx * 2] = make_float2(d, cutv * tsj);
        }
        // zero-pad up to 3 tail entries so the drain can read in groups of 4
        if (lane < 3) *(float2*)&qbuf[qb + (ns + lane) * 2] = make_float2(0.0f, 0.0f);

        for (int e = 0; e < ns; e += 4) {
            const float2 dm = *(const float2*)&qbuf[qb + (e + slot) * 2];
            const float diff = dm.x - c;
            const float ex = __expf(diff * diff * -36.0f);   // 1/w^2 = 36
            acc0 += ex * fmaxf(dm.y, 0.0f);
            acc1 += ex * fmaxf(-dm.y, 0.0f);
        }
    }

    // combine 4 slots: lanes r, r+16, r+32, r+48
    acc0 += __shfl_xor(acc0, 16, 64);
    acc0 += __shfl_xor(acc0, 32, 64);
    acc1 += __shfl_xor(acc1, 16, 64);
    acc1 += __shfl_xor(acc1, 32, 64);
    // lane r (0..15) holds env[r][0] in acc0, env[r][1] in acc1

    const float tsi = sdat[3 * N_ATOMS + i];
    const int   ti  = (tsi < 0.0f) ? 1 : 0;

    float* wsa = ws + (size_t)a * FSTRIDE;
    if (lane < 2)  wsa[lane] = (ti == lane) ? 1.0f : 0.0f;          // onehot
    if (lane < 16) *(float2*)&wsa[2 + 2 * lane] = make_float2(acc0, acc1);
}

// ---------------- K2: batched MLP 34 -> 64 -> 64 -> 64 ----------------
// 256 blocks x 32 atoms. Weights staged to LDS once per layer (shared by
// all 32 atoms -> 64x less weight traffic than per-atom MLP). Activation
// reads are wave-uniform LDS broadcasts; weight reads stride-1.
// thread = (unit t = tid&63, wave g = tid>>6); each thread computes 8 atoms.
__global__ __launch_bounds__(256) void k2_mlp(
    const float* __restrict__ ws,
    const float* __restrict__ W1, const float* __restrict__ b1,
    const float* __restrict__ W2, const float* __restrict__ b2,
    const float* __restrict__ W3, const float* __restrict__ b3,
    float*       __restrict__ out)   // [B*1024, 64]
{
    const int tid = threadIdx.x;
    const int t   = tid & 63;
    const int g   = tid >> 6;
    const int a0  = blockIdx.x * TM;

    __shared__ float w[64 * 64];        // current layer weights
    __shared__ float actA[TM * 64];     // feats (36 slots used) / h2
    __shared__ float actB[TM * 64];     // h1

    // stage feats tile (contiguous TM*FSTRIDE floats) + W1
    for (int idx = tid; idx < TM * FSTRIDE; idx += 256) {
        const int m = idx / FSTRIDE;
        const int k = idx - m * FSTRIDE;
        actA[m * 64 + k] = ws[(size_t)a0 * FSTRIDE + idx];
    }
    for (int idx = tid; idx < 34 * 64; idx += 256) w[idx] = W1[idx];
    __syncthreads();

    float acc[8];

    // ---- layer 1: 34 -> 64, SiLU ----
    {
        const float bias = b1[t];
#pragma unroll
        for (int j = 0; j < 8; ++j) acc[j] = bias;
        for (int k = 0; k < 34; ++k) {
            const float wv = w[k * 64 + t];
#pragma unroll
            for (int j = 0; j < 8; ++j)
                acc[j] += actA[(g * 8 + j) * 64 + k] * wv;   // uniform broadcast
        }
    }
    __syncthreads();                       // all reads of w / actA done
#pragma unroll
    for (int j = 0; j < 8; ++j) {
        float h = acc[j];
        h = h / (1.0f + __expf(-h));
        actB[(g * 8 + j) * 64 + t] = h;
    }
    for (int idx = tid; idx < 64 * 64; idx += 256) w[idx] = W2[idx];
    __syncthreads();

    // ---- layer 2: 64 -> 64, SiLU ----
    {
        const float bias = b2[t];
#pragma unroll
        for (int j = 0; j < 8; ++j) acc[j] = bias;
        for (int k = 0; k < 64; ++k) {
            const float wv = w[k * 64 + t];
#pragma unroll
            for (int j = 0; j < 8; ++j)
                acc[j] += actB[(g * 8 + j) * 64 + k] * wv;
        }
    }
    __syncthreads();
#pragma unroll
    for (int j = 0; j < 8; ++j) {
        float h = acc[j];
        h = h / (1.0f + __expf(-h));
        actA[(g * 8 + j) * 64 + t] = h;
    }
    for (int idx = tid; idx < 64 * 64; idx += 256) w[idx] = W3[idx];
    __syncthreads();

    // ---- layer 3: 64 -> 64, linear + store ----
    {
        const float bias = b3[t];
#pragma unroll
        for (int j = 0; j < 8; ++j) acc[j] = bias;
        for (int k = 0; k < 64; ++k) {
            const float wv = w[k * 64 + t];
#pragma unroll
            for (int j = 0; j < 8; ++j)
                acc[j] += actA[(g * 8 + j) * 64 + k] * wv;
        }
#pragma unroll
        for (int j = 0; j < 8; ++j)
            out[(size_t)(a0 + g * 8 + j) * HIDDEN + t] = acc[j];
    }
}

extern "C" void kernel_launch(void* const* d_in, const int* in_sizes, int n_in,
                              void* d_out, int out_size, void* d_ws, size_t ws_size,
                              hipStream_t stream) {
    const float* pos   = (const float*)d_in[0];
    const int*   types = (const int*)d_in[1];
    const float* W1    = (const float*)d_in[2];
    const float* b1    = (const float*)d_in[3];
    const float* W2    = (const float*)d_in[4];
    const float* b2    = (const float*)d_in[5];
    const float* W3    = (const float*)d_in[6];
    const float* b3    = (const float*)d_in[7];
    float*       out   = (float*)d_out;
    float*       feats = (float*)d_ws;          // [8192, FSTRIDE] = 1.18 MB

    const int BN = in_sizes[1];                 // B*N = 8192

    k1_env<<<BN / 4, 256, 0, stream>>>(pos, types, feats);
    k2_mlp<<<BN / TM, 256, 0, stream>>>(feats, W1, b1, W2, b2, W3, b3, out);
}